// Round 7
// baseline (3889.289 us; speedup 1.0000x reference)
//
#include <hip/hip_runtime.h>

#define TMASK  ((1u << 18) - 1u)
#define PRIME1 2654435761u
#define PRIME2 805459861u

// Naive 1-thread-per-point kernel (line-verified transcription) with the
// RES hypothesis flipped: harness numpy's SCALE = exp(ln(256)/16) rounds one
// ulp BELOW sqrt(2), so floor(16*SCALE^k) at even k gives 2^m - 1, not 2^m.
__global__ __launch_bounds__(64) void naive_hashmlp(
    const float* __restrict__ X, const float* __restrict__ Tb,
    const float* __restrict__ W1, const float* __restrict__ W2,
    float* __restrict__ Out) {
  __shared__ float hS[64 * 129];   // 33 KB: h[128] per point

  const int lane = threadIdx.x;            // 0..63 == point within block
  const int p = blockIdx.x * 64 + lane;    // global point id

  const float x0 = X[p * 3 + 0];
  const float x1 = X[p * 3 + 1];
  const float x2 = X[p * 3 + 2];

  // even-k levels: floor(16*SCALE^k) = 2^(4+k/2) - 1  (SCALE one ulp below sqrt2)
  constexpr float RESV[16] = {16.f, 22.f, 31.f, 45.f, 63.f, 90.f, 127.f, 181.f,
                              255.f, 362.f, 511.f, 724.f, 1023.f, 1448.f, 2047.f, 2896.f};

  float enc[35];
  enc[0] = x0; enc[1] = x1; enc[2] = x2;

#pragma unroll
  for (int lvl = 0; lvl < 16; ++lvl) {
    const float r = RESV[lvl];
    const float xs0 = x0 * r, xs1 = x1 * r, xs2 = x2 * r;     // plain f32, like jax
    const float fx = floorf(xs0), fy = floorf(xs1), fz = floorf(xs2);
    const float tx = xs0 - fx, ty = xs1 - fy, tz = xs2 - fz;
    const float wx = tx * tx * (3.f - 2.f * tx);
    const float wy = ty * ty * (3.f - 2.f * ty);
    const float wz = tz * tz * (3.f - 2.f * tz);
    const int cx = (int)fx, cy = (int)fy, cz = (int)fz;
    const float* tl = Tb + ((size_t)lvl << 19);               // level base (T*F floats)
    float a0 = 0.f, a1 = 0.f;
#pragma unroll
    for (int c = 0; c < 8; ++c) {                             // OFFS order: c = i*4 + j*2 + k
      const int i = (c >> 2) & 1, j = (c >> 1) & 1, k = c & 1;
      unsigned hh = ((unsigned)(cx + i))
                  ^ ((unsigned)(cy + j)) * PRIME1
                  ^ ((unsigned)(cz + k)) * PRIME2;
      hh &= TMASK;
      const float wt = (i ? wx : 1.f - wx) * (j ? wy : 1.f - wy) * (k ? wz : 1.f - wz);
      a0 = fmaf(tl[2 * hh + 0], wt, a0);
      a1 = fmaf(tl[2 * hh + 1], wt, a1);
    }
    enc[3 + 2 * lvl] = a0;
    enc[4 + 2 * lvl] = a1;
  }

  // ---- layer 1: h[j] = relu(sum_k enc[k] * W1[k][j]), 4-col tiles ----
  float* hrow = &hS[lane * 129];
  for (int j4 = 0; j4 < 32; ++j4) {
    float a0 = 0.f, a1 = 0.f, a2 = 0.f, a3 = 0.f;
#pragma unroll
    for (int k = 0; k < 35; ++k) {
      const float e = enc[k];
      const float* wr = &W1[k * 128 + j4 * 4];   // wave-uniform address
      a0 = fmaf(e, wr[0], a0);
      a1 = fmaf(e, wr[1], a1);
      a2 = fmaf(e, wr[2], a2);
      a3 = fmaf(e, wr[3], a3);
    }
    hrow[j4 * 4 + 0] = fmaxf(a0, 0.f);
    hrow[j4 * 4 + 1] = fmaxf(a1, 0.f);
    hrow[j4 * 4 + 2] = fmaxf(a2, 0.f);
    hrow[j4 * 4 + 3] = fmaxf(a3, 0.f);
  }

  // ---- layer 2: out[o] = sum_k h[k] * W2[k][o], 4-col tiles + tail col ----
  float* orow = &Out[(size_t)p * 129];
  for (int o4 = 0; o4 < 32; ++o4) {
    float a0 = 0.f, a1 = 0.f, a2 = 0.f, a3 = 0.f;
    for (int k = 0; k < 128; ++k) {
      const float hv = hrow[k];
      const float* wr = &W2[k * 129 + o4 * 4];   // wave-uniform address
      a0 = fmaf(hv, wr[0], a0);
      a1 = fmaf(hv, wr[1], a1);
      a2 = fmaf(hv, wr[2], a2);
      a3 = fmaf(hv, wr[3], a3);
    }
    orow[o4 * 4 + 0] = a0;
    orow[o4 * 4 + 1] = a1;
    orow[o4 * 4 + 2] = a2;
    orow[o4 * 4 + 3] = a3;
  }
  {
    float a0 = 0.f, a1 = 0.f;
    for (int k = 0; k < 128; k += 2) {
      a0 = fmaf(hrow[k],     W2[k * 129 + 128],       a0);
      a1 = fmaf(hrow[k + 1], W2[(k + 1) * 129 + 128], a1);
    }
    orow[128] = a0 + a1;
  }
}

extern "C" void kernel_launch(void* const* d_in, const int* in_sizes, int n_in,
                              void* d_out, int out_size, void* d_ws, size_t ws_size,
                              hipStream_t stream) {
  const float* X  = (const float*)d_in[0];
  const float* Tb = (const float*)d_in[1];
  const float* W1 = (const float*)d_in[2];
  const float* W2 = (const float*)d_in[3];
  float* Out = (float*)d_out;

  const int N = in_sizes[0] / 3;     // 1<<20
  const int nBlocks = N / 64;        // 16384
  naive_hashmlp<<<nBlocks, 64, 0, stream>>>(X, Tb, W1, W2, Out);
}

// Round 8
// 1207.573 us; speedup vs baseline: 3.2207x; 3.2207x over previous
//
#include <hip/hip_runtime.h>

typedef __attribute__((ext_vector_type(8))) short short8;
typedef __attribute__((ext_vector_type(4))) float f32x4;

#define TMASK  ((1u << 18) - 1u)
#define PRIME1 2654435761u
#define PRIME2 805459861u

// floor(16 * SCALE^k) where numpy's SCALE = exp(ln(256)/16) rounds one ulp
// BELOW sqrt(2): even-k levels land at 2^m - 1. Verified: round-7 PASS.
__constant__ float c_res[16] = {16.f, 22.f, 31.f, 45.f, 63.f, 90.f, 127.f, 181.f,
                                255.f, 362.f, 511.f, 724.f, 1023.f, 1448.f, 2047.f, 2896.f};

// round-to-nearest-even f32 -> bf16
__device__ __forceinline__ unsigned short rne_bf16(float v) {
  unsigned u = __builtin_bit_cast(unsigned, v);
  return (unsigned short)((u + 0x7fffu + ((u >> 16) & 1u)) >> 16);
}
__device__ __forceinline__ float b2f(unsigned short h) {
  unsigned u = (unsigned)h << 16;
  return __builtin_bit_cast(float, u);
}

// Fused hash-grid encode -> MLP(35->128 relu ->129), double-bf16 split MFMA
// (3 terms: hh+hl+lh, fp32 accum). Output staged in LDS, stored as whole lines.
__global__ __launch_bounds__(256) void fused_hashmlp(
    const float* __restrict__ X, const float* __restrict__ Tb,
    const float* __restrict__ W1, const float* __restrict__ W2,
    float* __restrict__ Out, int nChunks) {
  // Carved LDS, 147968 B total. Out-tile (33024 B) overlays enc+h (dead by then).
  __shared__ __align__(16) unsigned char lds[147968];
  unsigned short* w1hS = (unsigned short*)lds;                 // [128][64]  16384 B
  unsigned short* w1lS = w1hS + 128 * 64;                      //            16384 B
  unsigned short* w2hS = (unsigned short*)(lds + 32768);       // [129][128] 33024 B
  unsigned short* w2lS = w2hS + 129 * 128;                     //            33024 B
  unsigned short* enchS = (unsigned short*)(lds + 98816);      // [64][64]    8192 B
  unsigned short* enclS = enchS + 64 * 64;                     //             8192 B
  float*          hS    = (float*)(lds + 115200);              // [64][128]  32768 B
  float*          outS  = (float*)(lds + 98816);               // [64][129] overlay

  const int tid = threadIdx.x;

  // ---- Phase A: weights -> hi/lo bf16 LDS (transposed, chunk-swizzled) ----
  for (int idx = tid; idx < 128 * 64; idx += 256) {
    int k = idx >> 7;
    int col = idx & 127;
    float v = 0.f;
    if (k < 35) {
      int r = (k < 32) ? (k + 3) : (k - 32);   // row perm: features first, xyz at k=32..34
      v = W1[r * 128 + col];
    }
    unsigned short hi = rne_bf16(v);
    unsigned short lo = rne_bf16(v - b2f(hi));
    int a = col * 64 + (k ^ ((col & 7) << 3));
    w1hS[a] = hi; w1lS[a] = lo;
  }
  for (int idx = tid; idx < 129 * 128; idx += 256) {
    int k = idx / 129;
    int col = idx - k * 129;
    float v = W2[k * 129 + col];
    unsigned short hi = rne_bf16(v);
    unsigned short lo = rne_bf16(v - b2f(hi));
    int a = col * 128 + (k ^ ((col & 7) << 3));
    w2hS[a] = hi; w2lS[a] = lo;
  }
  __syncthreads();

  const int p = tid >> 2;      // point within chunk (0..63)
  const int s = tid & 3;       // sub-thread: levels 4s..4s+3
  const int lane = tid & 63;
  const int w = tid >> 6;      // wave id (row-tile)

  for (int chunk = blockIdx.x; chunk < nChunks; chunk += gridDim.x) {
    const int row0 = chunk * 64;

    // ---- Phase B: encode 4 levels per thread (plain f32, jax semantics) ----
    {
      const int gp = row0 + p;
      const float x0 = X[gp * 3 + 0];
      const float x1 = X[gp * 3 + 1];
      const float x2 = X[gp * 3 + 2];
      short8 pkh, pkl;
#pragma unroll
      for (int li = 0; li < 4; ++li) {
        const int lvl = (s << 2) + li;
        const float r = c_res[lvl];
        const float xs0 = x0 * r, xs1 = x1 * r, xs2 = x2 * r;
        const float f0 = floorf(xs0), f1 = floorf(xs1), f2 = floorf(xs2);
        const float t0 = xs0 - f0, t1 = xs1 - f1, t2 = xs2 - f2;
        const float w0 = t0 * t0 * (3.f - 2.f * t0);
        const float w1v = t1 * t1 * (3.f - 2.f * t1);
        const float w2v = t2 * t2 * (3.f - 2.f * t2);
        const unsigned cx0 = (unsigned)(int)f0;
        const unsigned hy0 = (unsigned)(int)f1 * PRIME1, hy1 = hy0 + PRIME1;
        const unsigned hz0 = (unsigned)(int)f2 * PRIME2, hz1 = hz0 + PRIME2;
        const float2* tab = reinterpret_cast<const float2*>(Tb) + ((size_t)lvl << 18);
        float a0 = 0.f, a1 = 0.f;
#pragma unroll
        for (int c = 0; c < 8; ++c) {  // OFFS order: c = i*4 + j*2 + k
          const unsigned hx = cx0 + (unsigned)((c >> 2) & 1);
          const unsigned hh = (hx ^ ((c & 2) ? hy1 : hy0) ^ ((c & 1) ? hz1 : hz0)) & TMASK;
          const float2 f = tab[hh];
          const float wt = (((c >> 2) & 1) ? w0 : 1.f - w0) *
                           (((c >> 1) & 1) ? w1v : 1.f - w1v) *
                           (((c & 1)) ? w2v : 1.f - w2v);
          a0 = fmaf(f.x, wt, a0);
          a1 = fmaf(f.y, wt, a1);
        }
        unsigned short h0 = rne_bf16(a0), h1 = rne_bf16(a1);
        pkh[li * 2 + 0] = (short)h0;
        pkh[li * 2 + 1] = (short)h1;
        pkl[li * 2 + 0] = (short)rne_bf16(a0 - b2f(h0));
        pkl[li * 2 + 1] = (short)rne_bf16(a1 - b2f(h1));
      }
      const int coff = (s ^ (p & 7)) << 3;
      *reinterpret_cast<short8*>(&enchS[p * 64 + coff]) = pkh;
      *reinterpret_cast<short8*>(&enclS[p * 64 + coff]) = pkl;
      short8 zh, zl;
#pragma unroll
      for (int e = 0; e < 8; ++e) { zh[e] = 0; zl[e] = 0; }
      if (s == 0) {
        unsigned short hx0 = rne_bf16(x0), hx1 = rne_bf16(x1), hx2 = rne_bf16(x2);
        zh[0] = (short)hx0; zh[1] = (short)hx1; zh[2] = (short)hx2;
        zl[0] = (short)rne_bf16(x0 - b2f(hx0));
        zl[1] = (short)rne_bf16(x1 - b2f(hx1));
        zl[2] = (short)rne_bf16(x2 - b2f(hx2));
      }
      const int coff2 = ((4 + s) ^ (p & 7)) << 3;
      *reinterpret_cast<short8*>(&enchS[p * 64 + coff2]) = zh;
      *reinterpret_cast<short8*>(&enclS[p * 64 + coff2]) = zl;
    }
    __syncthreads();

    // ---- Phase C: layer 1 (3-term split MFMA), wave w owns rows 16w..16w+15 ----
    f32x4 acc1[8];
#pragma unroll
    for (int c = 0; c < 8; ++c) acc1[c] = (f32x4){0.f, 0.f, 0.f, 0.f};
    {
      const int arow = (w << 4) + (lane & 15);
#pragma unroll
      for (int kc = 0; kc < 2; ++kc) {
        const int c8 = kc * 4 + (lane >> 4);
        const int aoff = arow * 64 + ((c8 ^ (arow & 7)) << 3);
        const short8 ah = *reinterpret_cast<const short8*>(&enchS[aoff]);
        const short8 al = *reinterpret_cast<const short8*>(&enclS[aoff]);
#pragma unroll
        for (int c = 0; c < 8; ++c) {
          const int bcol = c * 16 + (lane & 15);
          const int boff = bcol * 64 + ((c8 ^ (bcol & 7)) << 3);
          const short8 bh = *reinterpret_cast<const short8*>(&w1hS[boff]);
          const short8 bl = *reinterpret_cast<const short8*>(&w1lS[boff]);
          acc1[c] = __builtin_amdgcn_mfma_f32_16x16x32_bf16(ah, bh, acc1[c], 0, 0, 0);
          acc1[c] = __builtin_amdgcn_mfma_f32_16x16x32_bf16(ah, bl, acc1[c], 0, 0, 0);
          acc1[c] = __builtin_amdgcn_mfma_f32_16x16x32_bf16(al, bh, acc1[c], 0, 0, 0);
        }
      }
    }
    // ---- Phase D: relu -> hS (fp32, 16B-chunk swizzled) ----
#pragma unroll
    for (int c = 0; c < 8; ++c) {
#pragma unroll
      for (int r = 0; r < 4; ++r) {
        const int row = (w << 4) + (lane >> 4) * 4 + r;
        const int col = c * 16 + (lane & 15);
        const int cc = (col >> 2) ^ (row & 7);
        hS[row * 128 + (cc << 2) + (col & 3)] = fmaxf(acc1[c][r], 0.f);
      }
    }
    __syncthreads();

    // ---- Phase E: layer 2 (split h in registers, 3-term MFMA) ----
    {
      const int arow = (w << 4) + (lane & 15);
      short8 a2h[4], a2l[4];
#pragma unroll
      for (int kc = 0; kc < 4; ++kc) {
        const int c8 = kc * 4 + (lane >> 4);
        const int base = arow * 128;
        const int cc0 = (2 * c8) ^ (arow & 7);
        const int cc1 = (2 * c8 + 1) ^ (arow & 7);
        const f32x4 q0 = *reinterpret_cast<const f32x4*>(&hS[base + (cc0 << 2)]);
        const f32x4 q1 = *reinterpret_cast<const f32x4*>(&hS[base + (cc1 << 2)]);
#pragma unroll
        for (int e = 0; e < 4; ++e) {
          unsigned short hi = rne_bf16(q0[e]);
          a2h[kc][e] = (short)hi;
          a2l[kc][e] = (short)rne_bf16(q0[e] - b2f(hi));
        }
#pragma unroll
        for (int e = 0; e < 4; ++e) {
          unsigned short hi = rne_bf16(q1[e]);
          a2h[kc][4 + e] = (short)hi;
          a2l[kc][4 + e] = (short)rne_bf16(q1[e] - b2f(hi));
        }
      }
      __syncthreads();   // a2 fragments in regs; enc+h now dead -> outS may overlay

#pragma unroll
      for (int c = 0; c < 9; ++c) {
        f32x4 acc = (f32x4){0.f, 0.f, 0.f, 0.f};
        int bcol = c * 16 + (lane & 15);
        if (bcol > 128) bcol = 128;   // clamp: cols 129..143 masked below
#pragma unroll
        for (int kc = 0; kc < 4; ++kc) {
          const int c8 = kc * 4 + (lane >> 4);
          const int boff = bcol * 128 + ((c8 ^ (bcol & 7)) << 3);
          const short8 bh = *reinterpret_cast<const short8*>(&w2hS[boff]);
          const short8 bl = *reinterpret_cast<const short8*>(&w2lS[boff]);
          acc = __builtin_amdgcn_mfma_f32_16x16x32_bf16(a2h[kc], bh, acc, 0, 0, 0);
          acc = __builtin_amdgcn_mfma_f32_16x16x32_bf16(a2h[kc], bl, acc, 0, 0, 0);
          acc = __builtin_amdgcn_mfma_f32_16x16x32_bf16(a2l[kc], bh, acc, 0, 0, 0);
        }
        const int col = c * 16 + (lane & 15);
        if (col < 129) {
#pragma unroll
          for (int r = 0; r < 4; ++r) {
            const int lrow = (w << 4) + (lane >> 4) * 4 + r;
            outS[lrow * 129 + col] = acc[r];
          }
        }
      }
    }
    __syncthreads();

    // ---- Phase F: linear whole-line store: 64*129 floats = 516 cache lines ----
    {
      float* dst = Out + (size_t)row0 * 129;      // byte offset row0*516, 64B-aligned
      const f32x4* src = (const f32x4*)outS;
      for (int i = tid; i < 2064; i += 256)       // 2064 = 64*129/4
        *reinterpret_cast<f32x4*>(dst + 4 * i) = src[i];
    }
    __syncthreads();   // outS/enc region reused next iteration
  }
}

extern "C" void kernel_launch(void* const* d_in, const int* in_sizes, int n_in,
                              void* d_out, int out_size, void* d_ws, size_t ws_size,
                              hipStream_t stream) {
  const float* X  = (const float*)d_in[0];
  const float* Tb = (const float*)d_in[1];
  const float* W1 = (const float*)d_in[2];
  const float* W2 = (const float*)d_in[3];
  float* Out = (float*)d_out;

  const int N = in_sizes[0] / 3;     // 1<<20
  const int nChunks = N / 64;        // 16384
  int grid = nChunks < 1024 ? nChunks : 1024;
  fused_hashmlp<<<grid, 256, 0, stream>>>(X, Tb, W1, W2, Out, nChunks);
}